// Round 7
// baseline (26.934 us; speedup 1.0000x reference)
//
#include <hip/hip_runtime.h>

#define B_   1024
#define DIM_ 512
#define L_   512
#define NOUT 1536
#define G_   32    // interpolation grid points per batch
#define LDA  40    // LDS row stride in ushorts (80 B): 2-way-max bank aliasing
#define BM   128   // batch rows per block
#define BN   64    // out cols per block

typedef __attribute__((ext_vector_type(8))) short short8;
typedef __attribute__((ext_vector_type(4))) float f32x4;

// packed fp32x2 -> bf16x2 (RNE), one VALU op
__device__ __forceinline__ unsigned int cvtpk(float lo, float hi) {
  unsigned int r;
  asm("v_cvt_pk_bf16_f32 %0, %1, %2" : "=v"(r) : "v"(lo), "v"(hi));
  return r;
}

// ---------------- Kernel A: fused cvt + MFMA GEMM + in_proj ----------------
// C[b,o] = sum_k x[b,k]*w[o,k]. 128x64 tile/block, BK=32, 4 waves each owning
// a 32x64 stripe. fp32 loaded from global, packed-converted to bf16 during
// LDS staging. Double-buffered LDS: one barrier per K-step.
__global__ __launch_bounds__(256) void gemm_kernel(
    const float* __restrict__ x, const float* __restrict__ w,
    const float* __restrict__ ipw, const float* __restrict__ ipb,
    float* __restrict__ qp, float* __restrict__ kvp)
{
  __shared__ unsigned short aT[2][BM * LDA];   // 20 KB
  __shared__ unsigned short bT[2][BN * LDA];   // 10 KB

  const int tid  = threadIdx.x;
  const int lane = tid & 63;
  const int wv   = tid >> 6;
  const int row0 = blockIdx.y * BM;
  const int col0 = blockIdx.x * BN;

  // staging: A 2 thr/row x 16 floats, B 4 thr/row x 8 floats
  const int sra = tid >> 1, sca = (tid & 1) * 16;
  const int srb = tid >> 2, scb = (tid & 3) * 8;
  const float* xg = &x[(size_t)(row0 + sra) * DIM_ + sca];
  const float* wg = &w[(size_t)(col0 + srb) * DIM_ + scb];
  const int aoffW = sra * LDA + sca;
  const int boffW = srb * LDA + scb;

  // fragment reads: wave wv owns rows [wv*32, wv*32+32), all 64 cols
  const int lm = lane & 15, kq = (lane >> 4) * 8;
  const int aoffR = (wv * 32 + lm) * LDA + kq;
  const int boffR = lm * LDA + kq;

  f32x4 acc[2][4] = {};

  float4 a0 = *(const float4*)(xg);
  float4 a1 = *(const float4*)(xg + 4);
  float4 a2 = *(const float4*)(xg + 8);
  float4 a3 = *(const float4*)(xg + 12);
  float4 b0 = *(const float4*)(wg);
  float4 b1 = *(const float4*)(wg + 4);
  {
    uint4 av0 = { cvtpk(a0.x, a0.y), cvtpk(a0.z, a0.w), cvtpk(a1.x, a1.y), cvtpk(a1.z, a1.w) };
    uint4 av1 = { cvtpk(a2.x, a2.y), cvtpk(a2.z, a2.w), cvtpk(a3.x, a3.y), cvtpk(a3.z, a3.w) };
    uint4 bv  = { cvtpk(b0.x, b0.y), cvtpk(b0.z, b0.w), cvtpk(b1.x, b1.y), cvtpk(b1.z, b1.w) };
    *(uint4*)&aT[0][aoffW]     = av0;
    *(uint4*)&aT[0][aoffW + 8] = av1;
    *(uint4*)&bT[0][boffW]     = bv;
  }
  __syncthreads();

  int p = 0;
  for (int k0 = 32; k0 <= DIM_; k0 += 32) {
    if (k0 < DIM_) {   // next chunk's global loads — latency hides under MFMA
      a0 = *(const float4*)(xg + k0);
      a1 = *(const float4*)(xg + k0 + 4);
      a2 = *(const float4*)(xg + k0 + 8);
      a3 = *(const float4*)(xg + k0 + 12);
      b0 = *(const float4*)(wg + k0);
      b1 = *(const float4*)(wg + k0 + 4);
    }
    short8 af0 = *(const short8*)&aT[p][aoffR];
    short8 af1 = *(const short8*)&aT[p][aoffR + 16 * LDA];
    short8 bf0 = *(const short8*)&bT[p][boffR];
    short8 bf1 = *(const short8*)&bT[p][boffR + 16 * LDA];
    short8 bf2 = *(const short8*)&bT[p][boffR + 32 * LDA];
    short8 bf3 = *(const short8*)&bT[p][boffR + 48 * LDA];
    acc[0][0] = __builtin_amdgcn_mfma_f32_16x16x32_bf16(af0, bf0, acc[0][0], 0, 0, 0);
    acc[0][1] = __builtin_amdgcn_mfma_f32_16x16x32_bf16(af0, bf1, acc[0][1], 0, 0, 0);
    acc[0][2] = __builtin_amdgcn_mfma_f32_16x16x32_bf16(af0, bf2, acc[0][2], 0, 0, 0);
    acc[0][3] = __builtin_amdgcn_mfma_f32_16x16x32_bf16(af0, bf3, acc[0][3], 0, 0, 0);
    acc[1][0] = __builtin_amdgcn_mfma_f32_16x16x32_bf16(af1, bf0, acc[1][0], 0, 0, 0);
    acc[1][1] = __builtin_amdgcn_mfma_f32_16x16x32_bf16(af1, bf1, acc[1][1], 0, 0, 0);
    acc[1][2] = __builtin_amdgcn_mfma_f32_16x16x32_bf16(af1, bf2, acc[1][2], 0, 0, 0);
    acc[1][3] = __builtin_amdgcn_mfma_f32_16x16x32_bf16(af1, bf3, acc[1][3], 0, 0, 0);
    if (k0 < DIM_) {
      uint4 av0 = { cvtpk(a0.x, a0.y), cvtpk(a0.z, a0.w), cvtpk(a1.x, a1.y), cvtpk(a1.z, a1.w) };
      uint4 av1 = { cvtpk(a2.x, a2.y), cvtpk(a2.z, a2.w), cvtpk(a3.x, a3.y), cvtpk(a3.z, a3.w) };
      uint4 bv  = { cvtpk(b0.x, b0.y), cvtpk(b0.z, b0.w), cvtpk(b1.x, b1.y), cvtpk(b1.z, b1.w) };
      *(uint4*)&aT[p ^ 1][aoffW]     = av0;
      *(uint4*)&aT[p ^ 1][aoffW + 8] = av1;
      *(uint4*)&bT[p ^ 1][boffW]     = bv;
      __syncthreads();
      p ^= 1;
    }
  }

  const float pw0 = ipw[0], pw1 = ipw[1], pw2 = ipw[2];
  const float pb0 = ipb[0], pb1 = ipb[1], pb2 = ipb[2];
#pragma unroll
  for (int cj = 0; cj < 4; ++cj) {
    const int o = col0 + cj * 16 + lm;
    const int l = o / 3;
    const int c = o - 3 * l;
    const float pw = (c == 0) ? pw0 : ((c == 1) ? pw1 : pw2);
    const float pb = (c == 0) ? pb0 : ((c == 1) ? pb1 : pb2);
#pragma unroll
    for (int ri = 0; ri < 2; ++ri) {
#pragma unroll
      for (int r = 0; r < 4; ++r) {
        const int row = row0 + wv * 32 + ri * 16 + (lane >> 4) * 4 + r;
        const float v = fmaf(acc[ri][cj][r], pw, pb);
        if (c == 0) qp[(size_t)row * L_ + l] = v;
        else        kvp[(size_t)row * 2 * L_ + 2 * l + (c - 1)] = v;
      }
    }
  }
}

// ---------------- Kernel B: rank-1 attention via per-batch interpolation ---
// f(q) = sum_j exp(q k_j) v_j / sum_j exp(q k_j): evaluate on G_=32-pt grid
// over [qmin,qmax], Catmull-Rom interpolate the 512 rows. One block per batch.
// Grid eval: thread (g = tid&31, seg = tid>>5) sums 64 of 512 j-terms.
__global__ __launch_bounds__(256) void attn_kernel(
    const float* __restrict__ qp, const float* __restrict__ kvp,
    const float* __restrict__ x, const float* __restrict__ ow,
    const float* __restrict__ ob, float* __restrict__ out)
{
  __shared__ float2 kvs[L_];      // 4 KB
  __shared__ float2 part2[256];   // 2 KB
  __shared__ float  fgrid[G_];
  __shared__ float  red[8];
  const int b = blockIdx.x, tid = threadIdx.x;
  const float2* __restrict__ kvg = (const float2*)&kvp[(size_t)b * 2 * L_];

  float q0 = qp[(size_t)b * L_ + tid];
  float q1 = qp[(size_t)b * L_ + 256 + tid];
  float2 t0 = kvg[tid], t1 = kvg[tid + 256];
  kvs[tid] = t0; kvs[tid + 256] = t1;

  float qmn = fminf(q0, q1), qmx = fmaxf(q0, q1);
#pragma unroll
  for (int off = 32; off; off >>= 1) {
    qmn = fminf(qmn, __shfl_xor(qmn, off));
    qmx = fmaxf(qmx, __shfl_xor(qmx, off));
  }
  if ((tid & 63) == 0) { red[tid >> 6] = qmn; red[4 + (tid >> 6)] = qmx; }
  __syncthreads();
  qmn = fminf(fminf(red[0], red[1]), fminf(red[2], red[3]));
  qmx = fmaxf(fmaxf(red[4], red[5]), fmaxf(red[6], red[7]));

  const float L2E = 1.44269504f;
  const float range = qmx - qmn;
  const float hstep = range * (1.f / (G_ - 1));
  const int g   = tid & (G_ - 1);      // grid point 0..31
  const int seg = tid >> 5;            // j-segment 0..7 (64 terms each)
  const float gq = (qmn + hstep * (float)g) * L2E;
  float num = 0.f, den = 0.f;
  const float4* kv4 = (const float4*)&kvs[seg * 64];
#pragma unroll 4
  for (int j = 0; j < 32; ++j) {
    float4 pr = kv4[j];                // k,v,k,v (half-wave-uniform broadcast)
    float e0 = __builtin_amdgcn_exp2f(gq * pr.x);
    den += e0; num = fmaf(e0, pr.y, num);
    float e1 = __builtin_amdgcn_exp2f(gq * pr.z);
    den += e1; num = fmaf(e1, pr.w, num);
  }
  part2[tid] = make_float2(num, den);
  __syncthreads();
  if (tid < G_) {
    float nsum = 0.f, dsum = 0.f;
#pragma unroll
    for (int s = 0; s < 8; ++s) {
      float2 pp = part2[tid + 32 * s];
      nsum += pp.x; dsum += pp.y;
    }
    fgrid[tid] = nsum / dsum;
  }
  __syncthreads();

  const float inv_h = (range > 1e-20f) ? (float)(G_ - 1) / range : 0.f;
  const float w0 = ow[0], b0 = ob[0];
#pragma unroll
  for (int ii = 0; ii < 2; ++ii) {
    const float q = ii ? q1 : q0;
    float u = (q - qmn) * inv_h;
    u = fminf(fmaxf(u, 0.f), (float)(G_ - 1));
    int gi = (int)u;
    gi = min(gi, G_ - 2);
    const float t = u - (float)gi;
    const float p0 = fgrid[max(gi - 1, 0)];
    const float p1 = fgrid[gi];
    const float p2 = fgrid[gi + 1];
    const float p3 = fgrid[min(gi + 2, G_ - 1)];
    // Catmull-Rom
    const float f = 0.5f * (2.f * p1 + t * ((p2 - p0)
                  + t * ((2.f * p0 - 5.f * p1 + 4.f * p2 - p3)
                  + t * (3.f * (p1 - p2) + p3 - p0))));
    const int i = ii * 256 + tid;
    out[(size_t)b * L_ + i] = fmaf(f, w0, b0) + x[(size_t)b * L_ + i];
  }
}

extern "C" void kernel_launch(void* const* d_in, const int* in_sizes, int n_in,
                              void* d_out, int out_size, void* d_ws, size_t ws_size,
                              hipStream_t stream) {
  const float* x     = (const float*)d_in[0];
  const float* qkv_w = (const float*)d_in[1];
  const float* ipw   = (const float*)d_in[2];
  const float* ipb   = (const float*)d_in[3];
  const float* ow    = (const float*)d_in[4];
  const float* ob    = (const float*)d_in[5];
  float* out = (float*)d_out;

  char* ws = (char*)d_ws;
  float* qp  = (float*)(ws);            // 2.0 MB
  float* kvp = (float*)(ws + 2097152);  // 4.0 MB

  dim3 gA(NOUT / BN, B_ / BM);          // 24 x 8 = 192 blocks
  gemm_kernel<<<gA, dim3(256), 0, stream>>>(x, qkv_w, ipw, ipb, qp, kvp);

  attn_kernel<<<dim3(B_), dim3(256), 0, stream>>>(qp, kvp, x, ow, ob, out);
}

// Round 8
// 22.783 us; speedup vs baseline: 1.1822x; 1.1822x over previous
//
#include <hip/hip_runtime.h>

#define B_   1024
#define DIM_ 512
#define L_   512
#define NOUT 1536
#define G_   32    // interpolation grid points per batch
#define LDA  40    // LDS row stride in ushorts (80 B): 2-way-max bank aliasing

typedef __attribute__((ext_vector_type(8))) short short8;
typedef __attribute__((ext_vector_type(4))) float f32x4;

// packed fp32x2 -> bf16x2 (RNE), one VALU op
__device__ __forceinline__ unsigned int cvtpk(float lo, float hi) {
  unsigned int r;
  asm("v_cvt_pk_bf16_f32 %0, %1, %2" : "=v"(r) : "v"(lo), "v"(hi));
  return r;
}

// ---------------- Kernel A: fused cvt + MFMA GEMM, split-K=2 ---------------
// C[b,o] = sum_k x[b,k]*w[o,k]. 64x64 tile/block, BK=32, 4 waves each owning
// a 32x32 quadrant. blockIdx.z selects K-half [z*256, z*256+256) and output
// plane. Raw partial products stored (in_proj moved to attn). 768 blocks ->
// 3 blocks/CU, 12 waves/CU for latency hiding.
__global__ __launch_bounds__(256) void gemm_kernel(
    const float* __restrict__ x, const float* __restrict__ w,
    float* __restrict__ qp0, float* __restrict__ kvp0,
    float* __restrict__ qp1, float* __restrict__ kvp1)
{
  __shared__ unsigned short aT[2][64 * LDA];   // 10 KB
  __shared__ unsigned short bT[2][64 * LDA];   // 10 KB

  const int tid  = threadIdx.x;
  const int lane = tid & 63;
  const int wv   = tid >> 6;
  const int row0 = blockIdx.y * 64;
  const int col0 = blockIdx.x * 64;
  const int kz   = blockIdx.z;
  float* __restrict__ qp  = kz ? qp1 : qp0;
  float* __restrict__ kvp = kz ? kvp1 : kvp0;

  // staging assignment: row sr (0..63), k-chunk sc (0,8,16,24)
  const int sr = tid >> 2;
  const int sc = (tid & 3) * 8;
  const float* xg = &x[(size_t)(row0 + sr) * DIM_ + kz * 256 + sc];
  const float* wg = &w[(size_t)(col0 + sr) * DIM_ + kz * 256 + sc];
  const int soff = sr * LDA + sc;

  // fragment read assignment
  const int wr = wv >> 1, wc = wv & 1;
  const int lm = lane & 15;
  const int kq = (lane >> 4) * 8;
  const int aoff0 = (wr * 32 + lm) * LDA + kq;
  const int boff0 = (wc * 32 + lm) * LDA + kq;

  f32x4 acc00 = {0,0,0,0}, acc01 = {0,0,0,0}, acc10 = {0,0,0,0}, acc11 = {0,0,0,0};

  // prologue: stage first chunk into buffer 0
  float4 al = *(const float4*)(xg);
  float4 ah = *(const float4*)(xg + 4);
  float4 bl = *(const float4*)(wg);
  float4 bh = *(const float4*)(wg + 4);
  {
    uint4 av = { cvtpk(al.x, al.y), cvtpk(al.z, al.w), cvtpk(ah.x, ah.y), cvtpk(ah.z, ah.w) };
    uint4 bv = { cvtpk(bl.x, bl.y), cvtpk(bl.z, bl.w), cvtpk(bh.x, bh.y), cvtpk(bh.z, bh.w) };
    *(uint4*)&aT[0][soff] = av;
    *(uint4*)&bT[0][soff] = bv;
  }
  __syncthreads();

  int p = 0;
  for (int k0 = 32; k0 <= 256; k0 += 32) {
    if (k0 < 256) {   // next chunk's global loads — latency hides under MFMA
      al = *(const float4*)(xg + k0);
      ah = *(const float4*)(xg + k0 + 4);
      bl = *(const float4*)(wg + k0);
      bh = *(const float4*)(wg + k0 + 4);
    }
    short8 a0 = *(const short8*)&aT[p][aoff0];
    short8 a1 = *(const short8*)&aT[p][aoff0 + 16 * LDA];
    short8 b0 = *(const short8*)&bT[p][boff0];
    short8 b1 = *(const short8*)&bT[p][boff0 + 16 * LDA];
    acc00 = __builtin_amdgcn_mfma_f32_16x16x32_bf16(a0, b0, acc00, 0, 0, 0);
    acc01 = __builtin_amdgcn_mfma_f32_16x16x32_bf16(a0, b1, acc01, 0, 0, 0);
    acc10 = __builtin_amdgcn_mfma_f32_16x16x32_bf16(a1, b0, acc10, 0, 0, 0);
    acc11 = __builtin_amdgcn_mfma_f32_16x16x32_bf16(a1, b1, acc11, 0, 0, 0);
    if (k0 < 256) {
      uint4 av = { cvtpk(al.x, al.y), cvtpk(al.z, al.w), cvtpk(ah.x, ah.y), cvtpk(ah.z, ah.w) };
      uint4 bv = { cvtpk(bl.x, bl.y), cvtpk(bl.z, bl.w), cvtpk(bh.x, bh.y), cvtpk(bh.z, bh.w) };
      *(uint4*)&aT[p ^ 1][soff] = av;
      *(uint4*)&bT[p ^ 1][soff] = bv;
      __syncthreads();
      p ^= 1;
    }
  }

  f32x4 accs[2][2] = {{acc00, acc01}, {acc10, acc11}};
#pragma unroll
  for (int cj = 0; cj < 2; ++cj) {
    const int o = col0 + wc * 32 + cj * 16 + lm;
    const int l = o / 3;
    const int c = o - 3 * l;
#pragma unroll
    for (int ri = 0; ri < 2; ++ri) {
#pragma unroll
      for (int r = 0; r < 4; ++r) {
        const int row = row0 + wr * 32 + ri * 16 + (lane >> 4) * 4 + r;
        const float v = accs[ri][cj][r];
        if (c == 0) qp[(size_t)row * L_ + l] = v;
        else        kvp[(size_t)row * 2 * L_ + 2 * l + (c - 1)] = v;
      }
    }
  }
}

// ---------------- Kernel B: rank-1 attention via per-batch interpolation ---
// Sums the two split-K planes, applies in_proj affine, then evaluates
// f(q) = sum_j exp(q k_j) v_j / sum_j exp(q k_j) on a G_=32-pt grid over
// [qmin,qmax] and Catmull-Rom interpolates the 512 rows. One block per batch.
__global__ __launch_bounds__(256) void attn_kernel(
    const float* __restrict__ qp0, const float* __restrict__ kvp0,
    const float* __restrict__ qp1, const float* __restrict__ kvp1,
    const float* __restrict__ x,
    const float* __restrict__ ipw, const float* __restrict__ ipb,
    const float* __restrict__ ow, const float* __restrict__ ob,
    float* __restrict__ out)
{
  __shared__ float2 kvs[L_];      // 4 KB
  __shared__ float2 part2[256];   // 2 KB
  __shared__ float  fgrid[G_];
  __shared__ float  red[8];
  const int b = blockIdx.x, tid = threadIdx.x;
  const float2* __restrict__ kvg0 = (const float2*)&kvp0[(size_t)b * 2 * L_];
  const float2* __restrict__ kvg1 = (const float2*)&kvp1[(size_t)b * 2 * L_];

  const float pw0 = ipw[0], pw1 = ipw[1], pw2 = ipw[2];
  const float pb0 = ipb[0], pb1 = ipb[1], pb2 = ipb[2];

  float q0 = fmaf(qp0[(size_t)b * L_ + tid]       + qp1[(size_t)b * L_ + tid],       pw0, pb0);
  float q1 = fmaf(qp0[(size_t)b * L_ + 256 + tid] + qp1[(size_t)b * L_ + 256 + tid], pw0, pb0);
  float2 ta = kvg0[tid], tb = kvg1[tid];
  float2 tc = kvg0[tid + 256], td = kvg1[tid + 256];
  kvs[tid]       = make_float2(fmaf(ta.x + tb.x, pw1, pb1), fmaf(ta.y + tb.y, pw2, pb2));
  kvs[tid + 256] = make_float2(fmaf(tc.x + td.x, pw1, pb1), fmaf(tc.y + td.y, pw2, pb2));

  float qmn = fminf(q0, q1), qmx = fmaxf(q0, q1);
#pragma unroll
  for (int off = 32; off; off >>= 1) {
    qmn = fminf(qmn, __shfl_xor(qmn, off));
    qmx = fmaxf(qmx, __shfl_xor(qmx, off));
  }
  if ((tid & 63) == 0) { red[tid >> 6] = qmn; red[4 + (tid >> 6)] = qmx; }
  __syncthreads();
  qmn = fminf(fminf(red[0], red[1]), fminf(red[2], red[3]));
  qmx = fmaxf(fmaxf(red[4], red[5]), fmaxf(red[6], red[7]));

  const float L2E = 1.44269504f;
  const float range = qmx - qmn;
  const float hstep = range * (1.f / (G_ - 1));
  const int g   = tid & (G_ - 1);      // grid point 0..31
  const int seg = tid >> 5;            // j-segment 0..7 (64 terms each)
  const float gq = (qmn + hstep * (float)g) * L2E;
  float num = 0.f, den = 0.f;
  const float4* kv4 = (const float4*)&kvs[seg * 64];
#pragma unroll 4
  for (int j = 0; j < 32; ++j) {
    float4 pr = kv4[j];                // k,v,k,v (half-wave-uniform broadcast)
    float e0 = __builtin_amdgcn_exp2f(gq * pr.x);
    den += e0; num = fmaf(e0, pr.y, num);
    float e1 = __builtin_amdgcn_exp2f(gq * pr.z);
    den += e1; num = fmaf(e1, pr.w, num);
  }
  part2[tid] = make_float2(num, den);
  __syncthreads();
  if (tid < G_) {
    float nsum = 0.f, dsum = 0.f;
#pragma unroll
    for (int s = 0; s < 8; ++s) {
      float2 pp = part2[tid + 32 * s];
      nsum += pp.x; dsum += pp.y;
    }
    fgrid[tid] = nsum / dsum;
  }
  __syncthreads();

  const float inv_h = (range > 1e-20f) ? (float)(G_ - 1) / range : 0.f;
  const float w0 = ow[0], b0 = ob[0];
#pragma unroll
  for (int ii = 0; ii < 2; ++ii) {
    const float q = ii ? q1 : q0;
    float u = (q - qmn) * inv_h;
    u = fminf(fmaxf(u, 0.f), (float)(G_ - 1));
    int gi = (int)u;
    gi = min(gi, G_ - 2);
    const float t = u - (float)gi;
    const float p0 = fgrid[max(gi - 1, 0)];
    const float p1 = fgrid[gi];
    const float p2 = fgrid[gi + 1];
    const float p3 = fgrid[min(gi + 2, G_ - 1)];
    // Catmull-Rom
    const float f = 0.5f * (2.f * p1 + t * ((p2 - p0)
                  + t * ((2.f * p0 - 5.f * p1 + 4.f * p2 - p3)
                  + t * (3.f * (p1 - p2) + p3 - p0))));
    const int i = ii * 256 + tid;
    out[(size_t)b * L_ + i] = fmaf(f, w0, b0) + x[(size_t)b * L_ + i];
  }
}

extern "C" void kernel_launch(void* const* d_in, const int* in_sizes, int n_in,
                              void* d_out, int out_size, void* d_ws, size_t ws_size,
                              hipStream_t stream) {
  const float* x     = (const float*)d_in[0];
  const float* qkv_w = (const float*)d_in[1];
  const float* ipw   = (const float*)d_in[2];
  const float* ipb   = (const float*)d_in[3];
  const float* ow    = (const float*)d_in[4];
  const float* ob    = (const float*)d_in[5];
  float* out = (float*)d_out;

  char* ws = (char*)d_ws;
  float* qp0  = (float*)(ws);                  // 2.0 MB
  float* qp1  = (float*)(ws + 2097152);        // 2.0 MB
  float* kvp0 = (float*)(ws + 4194304);        // 4.0 MB
  float* kvp1 = (float*)(ws + 8388608);        // 4.0 MB  (total 12 MB)

  dim3 gA(NOUT / 64, B_ / 64, 2);              // 24 x 16 x 2 = 768 blocks
  gemm_kernel<<<gA, dim3(256), 0, stream>>>(x, qkv_w, qp0, kvp0, qp1, kvp1);

  attn_kernel<<<dim3(B_), dim3(256), 0, stream>>>(
      qp0, kvp0, qp1, kvp1, x, ipw, ipb, ow, ob, out);
}